// Round 1
// baseline (3237.769 us; speedup 1.0000x reference)
//
#include <hip/hip_runtime.h>
#include <math.h>

static inline size_t align256(size_t x) { return (x + 255) & ~size_t(255); }

// -------- scatter-add: agg[dst[e]] += h[src[e]], 16 floats/row --------
__global__ __launch_bounds__(256) void scatter16(const float4* __restrict__ h4,
                                                 const int* __restrict__ src,
                                                 const int* __restrict__ dst,
                                                 float* __restrict__ agg, int E) {
    int t = blockIdx.x * blockDim.x + threadIdx.x;
    int e = t >> 2, c = t & 3;
    if (e >= E) return;
    int s0 = src[e], d0 = dst[e];
    float4 v = h4[(size_t)s0 * 4 + c];
    float* p = agg + (size_t)d0 * 16 + c * 4;
    unsafeAtomicAdd(p + 0, v.x);
    unsafeAtomicAdd(p + 1, v.y);
    unsafeAtomicAdd(p + 2, v.z);
    unsafeAtomicAdd(p + 3, v.w);
}

// -------- scatter-add: agg[dst[e]] += h[src[e]], 64 floats/row --------
__global__ __launch_bounds__(256) void scatter64(const float4* __restrict__ h4,
                                                 const int* __restrict__ src,
                                                 const int* __restrict__ dst,
                                                 float* __restrict__ agg, int E) {
    int t = blockIdx.x * blockDim.x + threadIdx.x;
    int e = t >> 4, c = t & 15;
    if (e >= E) return;
    int s0 = src[e], d0 = dst[e];
    float4 v = h4[(size_t)s0 * 16 + c];
    float* p = agg + (size_t)d0 * 64 + c * 4;
    unsafeAtomicAdd(p + 0, v.x);
    unsafeAtomicAdd(p + 1, v.y);
    unsafeAtomicAdd(p + 2, v.z);
    unsafeAtomicAdd(p + 3, v.w);
}

// -------- y = relu(x @ W1 + b1), x:[BN,16], W1:[16,64] --------
__global__ __launch_bounds__(256) void lin1_relu(const float* __restrict__ x,
                                                 const float* __restrict__ W1,
                                                 const float* __restrict__ b1,
                                                 float* __restrict__ y, int BN) {
    __shared__ float Ws[16 * 64];
    __shared__ float xs[4][16];
    int tid = threadIdx.x;
    for (int i = tid; i < 16 * 64; i += 256) Ws[i] = W1[i];
    int node0 = blockIdx.x * 4;
    int r = tid >> 6, j = tid & 63;
    if (tid < 64) {
        int nn = tid >> 4, k = tid & 15;
        int node = node0 + nn;
        xs[nn][k] = (node < BN) ? x[(size_t)node * 16 + k] : 0.f;
    }
    __syncthreads();
    int node = node0 + r;
    if (node >= BN) return;
    float acc = b1[j];
#pragma unroll
    for (int k = 0; k < 16; ++k) acc = fmaf(xs[r][k], Ws[k * 64 + j], acc);
    y[(size_t)node * 64 + j] = fmaxf(acc, 0.f);
}

// -------- y = relu(x @ W2 + b2), x:[BN,64], W2:[64,64] --------
__global__ __launch_bounds__(256) void lin2_relu(const float* __restrict__ x,
                                                 const float* __restrict__ W2,
                                                 const float* __restrict__ b2,
                                                 float* __restrict__ y, int BN) {
    __shared__ float Ws[64 * 64];
    __shared__ float xs[4][64];
    int tid = threadIdx.x;
    for (int i = tid; i < 64 * 64; i += 256) Ws[i] = W2[i];
    int node0 = blockIdx.x * 4;
    int r = tid >> 6, j = tid & 63;
    int node = node0 + r;
    xs[r][j] = (node < BN) ? x[(size_t)node * 64 + j] : 0.f;
    __syncthreads();
    if (node >= BN) return;
    float acc = b2[j];
#pragma unroll
    for (int k = 0; k < 64; ++k) acc = fmaf(xs[r][k], Ws[k * 64 + j], acc);
    y[(size_t)node * 64 + j] = fmaxf(acc, 0.f);
}

// -------- per-graph mean over N nodes, 64 features --------
__global__ __launch_bounds__(256) void graph_mean(const float* __restrict__ h2,
                                                  float* __restrict__ mean, int N) {
    int b = blockIdx.x;
    int tid = threadIdx.x;
    int r = tid >> 6, f = tid & 63;
    const float* base = h2 + (size_t)b * N * 64;
    float acc = 0.f;
    for (int n = r; n < N; n += 4) acc += base[(size_t)n * 64 + f];
    __shared__ float red[4][64];
    red[r][f] = acc;
    __syncthreads();
    if (r == 0) {
        float s = red[0][f] + red[1][f] + red[2][f] + red[3][f];
        mean[b * 64 + f] = s / (float)N;
    }
}

// -------- per (graph, pathway): sum-pool L nodes, concat(mean, sum) . wlin, tanh --------
__global__ __launch_bounds__(256) void pathway_score(const float* __restrict__ h2,
                                                     const int* __restrict__ pathway,
                                                     const float* __restrict__ mean,
                                                     const float* __restrict__ wlin,
                                                     const float* __restrict__ blin,
                                                     float* __restrict__ s,
                                                     int B, int N, int P, int L) {
    int wid = (int)((blockIdx.x * blockDim.x + threadIdx.x) >> 6);
    int lane = threadIdx.x & 63;
    if (wid >= B * P) return;
    int b = wid / P, p = wid % P;
    const float* base = h2 + (size_t)b * N * 64;
    const int* path = pathway + (size_t)p * L;
    float acc = 0.f;
    for (int l = 0; l < L; ++l) {
        int idx = path[l];
        acc += base[(size_t)idx * 64 + lane];
    }
    float val = acc * wlin[64 + lane] + mean[b * 64 + lane] * wlin[lane];
#pragma unroll
    for (int off = 32; off >= 1; off >>= 1) val += __shfl_xor(val, off, 64);
    if (lane == 0) s[wid] = tanhf(val + blin[0]);
}

// -------- out = softmax(s @ Wout + bout), s:[B,P], Wout:[P,2] --------
__global__ __launch_bounds__(64) void out_softmax(const float* __restrict__ s,
                                                  const float* __restrict__ Wout,
                                                  const float* __restrict__ bout,
                                                  float* __restrict__ out, int B, int P) {
    __shared__ float logits[64];
    int tid = threadIdx.x;
    if (tid < B * 2) {
        int b = tid >> 1, k = tid & 1;
        float acc = bout[k];
        const float* sb = s + (size_t)b * P;
        for (int p = 0; p < P; ++p) acc = fmaf(sb[p], Wout[p * 2 + k], acc);
        logits[tid] = acc;
    }
    __syncthreads();
    if (tid < B) {
        float l0 = logits[tid * 2], l1 = logits[tid * 2 + 1];
        float m = fmaxf(l0, l1);
        float e0 = expf(l0 - m), e1 = expf(l1 - m);
        float inv = 1.f / (e0 + e1);
        out[tid * 2 + 0] = e0 * inv;
        out[tid * 2 + 1] = e1 * inv;
    }
}

extern "C" void kernel_launch(void* const* d_in, const int* in_sizes, int n_in,
                              void* d_out, int out_size, void* d_ws, size_t ws_size,
                              hipStream_t stream) {
    const float* h       = (const float*)d_in[0];
    const int*   src     = (const int*)d_in[1];
    const int*   dst     = (const int*)d_in[2];
    const int*   pathway = (const int*)d_in[3];
    // d_in[4] = num_graphs (scalar on device; B derived from out_size)
    const float* W1      = (const float*)d_in[5];
    const float* b1      = (const float*)d_in[6];
    const float* W2      = (const float*)d_in[7];
    const float* b2      = (const float*)d_in[8];
    const float* wlin    = (const float*)d_in[9];
    const float* blin    = (const float*)d_in[10];
    const float* Wout    = (const float*)d_in[11];
    const float* bout    = (const float*)d_in[12];
    float*       out     = (float*)d_out;

    const int BN = in_sizes[0] / 16;
    const int E  = in_sizes[1];
    const int P  = in_sizes[11] / 2;
    const int L  = in_sizes[3] / P;
    const int B  = out_size / 2;
    const int N  = BN / B;

    char* ws = (char*)d_ws;
    size_t o = 0;
    float* tmp0 = (float*)(ws + o); o += align256((size_t)BN * 16 * 4);
    float* h1   = (float*)(ws + o); o += align256((size_t)BN * 64 * 4);
    float* tmp1 = (float*)(ws + o); o += align256((size_t)BN * 64 * 4);
    float* h2   = (float*)(ws + o); o += align256((size_t)BN * 64 * 4);
    float* mean = (float*)(ws + o); o += align256((size_t)B * 64 * 4);
    float* sbuf = (float*)(ws + o); o += align256((size_t)B * P * 4);
    (void)ws_size; (void)n_in;

    // layer 1: tmp0 = h; tmp0[dst] += h[src]; h1 = relu(tmp0 @ W1 + b1)
    hipMemcpyAsync(tmp0, h, (size_t)BN * 16 * 4, hipMemcpyDeviceToDevice, stream);
    {
        int total = E * 4;
        scatter16<<<(total + 255) / 256, 256, 0, stream>>>((const float4*)h, src, dst, tmp0, E);
    }
    lin1_relu<<<(BN + 3) / 4, 256, 0, stream>>>(tmp0, W1, b1, h1, BN);

    // layer 2: tmp1 = h1; tmp1[dst] += h1[src]; h2 = relu(tmp1 @ W2 + b2)
    hipMemcpyAsync(tmp1, h1, (size_t)BN * 64 * 4, hipMemcpyDeviceToDevice, stream);
    {
        long long total = (long long)E * 16;
        scatter64<<<(int)((total + 255) / 256), 256, 0, stream>>>((const float4*)h1, src, dst, tmp1, E);
    }
    lin2_relu<<<(BN + 3) / 4, 256, 0, stream>>>(tmp1, W2, b2, h2, BN);

    // pooling head
    graph_mean<<<B, 256, 0, stream>>>(h2, mean, N);
    {
        int waves = B * P;
        pathway_score<<<(waves + 3) / 4, 256, 0, stream>>>(h2, pathway, mean, wlin, blin, sbuf,
                                                           B, N, P, L);
    }
    out_softmax<<<1, 64, 0, stream>>>(sbuf, Wout, bout, out, B, P);
}

// Round 2
// 1030.092 us; speedup vs baseline: 3.1432x; 3.1432x over previous
//
#include <hip/hip_runtime.h>
#include <math.h>

static inline size_t align256(size_t x) { return (x + 255) & ~size_t(255); }

// ============ CSR construction ============

__global__ __launch_bounds__(256) void csr_count(const int* __restrict__ dst,
                                                 int* __restrict__ counts, int E) {
    int e = blockIdx.x * blockDim.x + threadIdx.x;
    if (e >= E) return;
    atomicAdd(&counts[dst[e]], 1);
}

// per-block (1024 elems) sum of counts
__global__ __launch_bounds__(256) void block_reduce(const int* __restrict__ counts,
                                                    int* __restrict__ bsum, int BN) {
    __shared__ int red[256];
    int base = blockIdx.x * 1024;
    int s = 0;
    for (int k = threadIdx.x; k < 1024; k += 256) {
        int idx = base + k;
        s += (idx < BN) ? counts[idx] : 0;
    }
    red[threadIdx.x] = s;
    __syncthreads();
    for (int off = 128; off >= 1; off >>= 1) {
        if (threadIdx.x < off) red[threadIdx.x] += red[threadIdx.x + off];
        __syncthreads();
    }
    if (threadIdx.x == 0) bsum[blockIdx.x] = red[0];
}

// exclusive scan of nb (<=1024) block sums, single block of 1024 threads
__global__ __launch_bounds__(1024) void scan_small(const int* __restrict__ bsum,
                                                   int* __restrict__ bpre, int nb) {
    __shared__ int buf[1024];
    int tid = threadIdx.x;
    buf[tid] = (tid < nb) ? bsum[tid] : 0;
    __syncthreads();
    for (int off = 1; off < 1024; off <<= 1) {
        int v = (tid >= off) ? buf[tid - off] : 0;
        __syncthreads();
        buf[tid] += v;
        __syncthreads();
    }
    if (tid < nb) bpre[tid] = (tid == 0) ? 0 : buf[tid - 1];
}

// per-block exclusive scan (1024 elems, 4/thread) + add block prefix -> offsets
__global__ __launch_bounds__(256) void block_scan(const int* __restrict__ counts,
                                                  const int* __restrict__ bpre,
                                                  int* __restrict__ offs, int BN) {
    __shared__ int tsum[256];
    int base = blockIdx.x * 1024;
    int tbase = base + threadIdx.x * 4;
    int c0 = 0, c1 = 0, c2 = 0, c3 = 0;
    if (tbase + 0 < BN) c0 = counts[tbase + 0];
    if (tbase + 1 < BN) c1 = counts[tbase + 1];
    if (tbase + 2 < BN) c2 = counts[tbase + 2];
    if (tbase + 3 < BN) c3 = counts[tbase + 3];
    int local = c0 + c1 + c2 + c3;
    tsum[threadIdx.x] = local;
    __syncthreads();
    for (int off = 1; off < 256; off <<= 1) {
        int v = (threadIdx.x >= off) ? tsum[threadIdx.x - off] : 0;
        __syncthreads();
        tsum[threadIdx.x] += v;
        __syncthreads();
    }
    int prefix = bpre[blockIdx.x] + tsum[threadIdx.x] - local;  // exclusive
    if (tbase + 0 < BN) offs[tbase + 0] = prefix;
    prefix += c0;
    if (tbase + 1 < BN) offs[tbase + 1] = prefix;
    prefix += c1;
    if (tbase + 2 < BN) offs[tbase + 2] = prefix;
    prefix += c2;
    if (tbase + 3 < BN) offs[tbase + 3] = prefix;
}

__global__ __launch_bounds__(256) void csr_fill(const int* __restrict__ src,
                                                const int* __restrict__ dst,
                                                int* __restrict__ cursor,
                                                int* __restrict__ esrc, int E) {
    int e = blockIdx.x * blockDim.x + threadIdx.x;
    if (e >= E) return;
    int d = dst[e];
    int pos = atomicAdd(&cursor[d], 1);
    esrc[pos] = src[e];
}

// ============ gather (self + incoming neighbor sum) ============

// 16 floats/row: 4 lanes per node, float4 each
__global__ __launch_bounds__(256) void gather16(const float4* __restrict__ h4,
                                                const int* __restrict__ offs,
                                                const int* __restrict__ cnts,
                                                const int* __restrict__ esrc,
                                                float4* __restrict__ out4, int BN) {
    int t = blockIdx.x * blockDim.x + threadIdx.x;
    int i = t >> 2, c = t & 3;
    if (i >= BN) return;
    float4 acc = h4[(size_t)i * 4 + c];
    int start = offs[i], deg = cnts[i];
    for (int j = 0; j < deg; ++j) {
        int s = esrc[start + j];
        float4 v = h4[(size_t)s * 4 + c];
        acc.x += v.x; acc.y += v.y; acc.z += v.z; acc.w += v.w;
    }
    out4[(size_t)i * 4 + c] = acc;
}

// 64 floats/row: 16 lanes per node, float4 each
__global__ __launch_bounds__(256) void gather64(const float4* __restrict__ h4,
                                                const int* __restrict__ offs,
                                                const int* __restrict__ cnts,
                                                const int* __restrict__ esrc,
                                                float4* __restrict__ out4, int BN) {
    int t = blockIdx.x * blockDim.x + threadIdx.x;
    int i = t >> 4, c = t & 15;
    if (i >= BN) return;
    float4 acc = h4[(size_t)i * 16 + c];
    int start = offs[i], deg = cnts[i];
    for (int j = 0; j < deg; ++j) {
        int s = esrc[start + j];
        float4 v = h4[(size_t)s * 16 + c];
        acc.x += v.x; acc.y += v.y; acc.z += v.z; acc.w += v.w;
    }
    out4[(size_t)i * 16 + c] = acc;
}

// ============ dense layers ============

__global__ __launch_bounds__(256) void lin1_relu(const float* __restrict__ x,
                                                 const float* __restrict__ W1,
                                                 const float* __restrict__ b1,
                                                 float* __restrict__ y, int BN) {
    __shared__ float Ws[16 * 64];
    __shared__ float xs[4][16];
    int tid = threadIdx.x;
    for (int i = tid; i < 16 * 64; i += 256) Ws[i] = W1[i];
    int node0 = blockIdx.x * 4;
    int r = tid >> 6, j = tid & 63;
    if (tid < 64) {
        int nn = tid >> 4, k = tid & 15;
        int node = node0 + nn;
        xs[nn][k] = (node < BN) ? x[(size_t)node * 16 + k] : 0.f;
    }
    __syncthreads();
    int node = node0 + r;
    if (node >= BN) return;
    float acc = b1[j];
#pragma unroll
    for (int k = 0; k < 16; ++k) acc = fmaf(xs[r][k], Ws[k * 64 + j], acc);
    y[(size_t)node * 64 + j] = fmaxf(acc, 0.f);
}

__global__ __launch_bounds__(256) void lin2_relu(const float* __restrict__ x,
                                                 const float* __restrict__ W2,
                                                 const float* __restrict__ b2,
                                                 float* __restrict__ y, int BN) {
    __shared__ float Ws[64 * 64];
    __shared__ float xs[4][64];
    int tid = threadIdx.x;
    for (int i = tid; i < 64 * 64; i += 256) Ws[i] = W2[i];
    int node0 = blockIdx.x * 4;
    int r = tid >> 6, j = tid & 63;
    int node = node0 + r;
    xs[r][j] = (node < BN) ? x[(size_t)node * 64 + j] : 0.f;
    __syncthreads();
    if (node >= BN) return;
    float acc = b2[j];
#pragma unroll
    for (int k = 0; k < 64; ++k) acc = fmaf(xs[r][k], Ws[k * 64 + j], acc);
    y[(size_t)node * 64 + j] = fmaxf(acc, 0.f);
}

// ============ pooling head ============

__global__ __launch_bounds__(256) void graph_mean(const float* __restrict__ h2,
                                                  float* __restrict__ mean, int N) {
    int b = blockIdx.x;
    int tid = threadIdx.x;
    int r = tid >> 6, f = tid & 63;
    const float* base = h2 + (size_t)b * N * 64;
    float acc = 0.f;
    for (int n = r; n < N; n += 4) acc += base[(size_t)n * 64 + f];
    __shared__ float red[4][64];
    red[r][f] = acc;
    __syncthreads();
    if (r == 0) {
        float s = red[0][f] + red[1][f] + red[2][f] + red[3][f];
        mean[b * 64 + f] = s / (float)N;
    }
}

__global__ __launch_bounds__(256) void pathway_score(const float* __restrict__ h2,
                                                     const int* __restrict__ pathway,
                                                     const float* __restrict__ mean,
                                                     const float* __restrict__ wlin,
                                                     const float* __restrict__ blin,
                                                     float* __restrict__ s,
                                                     int B, int N, int P, int L) {
    int wid = (int)((blockIdx.x * blockDim.x + threadIdx.x) >> 6);
    int lane = threadIdx.x & 63;
    if (wid >= B * P) return;
    int b = wid / P, p = wid % P;
    const float* base = h2 + (size_t)b * N * 64;
    const int* path = pathway + (size_t)p * L;
    float acc = 0.f;
    for (int l = 0; l < L; ++l) {
        int idx = path[l];
        acc += base[(size_t)idx * 64 + lane];
    }
    float val = acc * wlin[64 + lane] + mean[b * 64 + lane] * wlin[lane];
#pragma unroll
    for (int off = 32; off >= 1; off >>= 1) val += __shfl_xor(val, off, 64);
    if (lane == 0) s[wid] = tanhf(val + blin[0]);
}

__global__ __launch_bounds__(64) void out_softmax(const float* __restrict__ s,
                                                  const float* __restrict__ Wout,
                                                  const float* __restrict__ bout,
                                                  float* __restrict__ out, int B, int P) {
    __shared__ float logits[64];
    int tid = threadIdx.x;
    if (tid < B * 2) {
        int b = tid >> 1, k = tid & 1;
        float acc = bout[k];
        const float* sb = s + (size_t)b * P;
        for (int p = 0; p < P; ++p) acc = fmaf(sb[p], Wout[p * 2 + k], acc);
        logits[tid] = acc;
    }
    __syncthreads();
    if (tid < B) {
        float l0 = logits[tid * 2], l1 = logits[tid * 2 + 1];
        float m = fmaxf(l0, l1);
        float e0 = expf(l0 - m), e1 = expf(l1 - m);
        float inv = 1.f / (e0 + e1);
        out[tid * 2 + 0] = e0 * inv;
        out[tid * 2 + 1] = e1 * inv;
    }
}

extern "C" void kernel_launch(void* const* d_in, const int* in_sizes, int n_in,
                              void* d_out, int out_size, void* d_ws, size_t ws_size,
                              hipStream_t stream) {
    const float* h       = (const float*)d_in[0];
    const int*   src     = (const int*)d_in[1];
    const int*   dst     = (const int*)d_in[2];
    const int*   pathway = (const int*)d_in[3];
    const float* W1      = (const float*)d_in[5];
    const float* b1      = (const float*)d_in[6];
    const float* W2      = (const float*)d_in[7];
    const float* b2      = (const float*)d_in[8];
    const float* wlin    = (const float*)d_in[9];
    const float* blin    = (const float*)d_in[10];
    const float* Wout    = (const float*)d_in[11];
    const float* bout    = (const float*)d_in[12];
    float*       out     = (float*)d_out;

    const int BN = in_sizes[0] / 16;
    const int E  = in_sizes[1];
    const int P  = in_sizes[11] / 2;
    const int L  = in_sizes[3] / P;
    const int B  = out_size / 2;
    const int N  = BN / B;
    const int nb = (BN + 1023) / 1024;  // scan blocks (<=1024 assumed)

    char* ws = (char*)d_ws;
    size_t o = 0;
    float* tmp0   = (float*)(ws + o); o += align256((size_t)BN * 16 * 4);
    float* h1     = (float*)(ws + o); o += align256((size_t)BN * 64 * 4);
    float* tmp1   = (float*)(ws + o); o += align256((size_t)BN * 64 * 4);
    float* h2     = (float*)(ws + o); o += align256((size_t)BN * 64 * 4);
    float* mean   = (float*)(ws + o); o += align256((size_t)B * 64 * 4);
    float* sbuf   = (float*)(ws + o); o += align256((size_t)B * P * 4);
    int*   counts = (int*)(ws + o);   o += align256((size_t)BN * 4);
    int*   offs   = (int*)(ws + o);   o += align256((size_t)BN * 4);
    int*   cursor = (int*)(ws + o);   o += align256((size_t)BN * 4);
    int*   esrc   = (int*)(ws + o);   o += align256((size_t)E * 4);
    int*   bsum   = (int*)(ws + o);   o += align256((size_t)nb * 4);
    int*   bpre   = (int*)(ws + o);   o += align256((size_t)nb * 4);
    (void)ws_size; (void)n_in;

    // ---- build CSR (dst -> list of src) ----
    hipMemsetAsync(counts, 0, (size_t)BN * 4, stream);
    csr_count<<<(E + 255) / 256, 256, 0, stream>>>(dst, counts, E);
    block_reduce<<<nb, 256, 0, stream>>>(counts, bsum, BN);
    scan_small<<<1, 1024, 0, stream>>>(bsum, bpre, nb);
    block_scan<<<nb, 256, 0, stream>>>(counts, bpre, offs, BN);
    hipMemcpyAsync(cursor, offs, (size_t)BN * 4, hipMemcpyDeviceToDevice, stream);
    csr_fill<<<(E + 255) / 256, 256, 0, stream>>>(src, dst, cursor, esrc, E);

    // ---- layer 1 ----
    gather16<<<(BN * 4 + 255) / 256, 256, 0, stream>>>((const float4*)h, offs, counts, esrc,
                                                       (float4*)tmp0, BN);
    lin1_relu<<<(BN + 3) / 4, 256, 0, stream>>>(tmp0, W1, b1, h1, BN);

    // ---- layer 2 ----
    gather64<<<(BN * 16 + 255) / 256, 256, 0, stream>>>((const float4*)h1, offs, counts, esrc,
                                                        (float4*)tmp1, BN);
    lin2_relu<<<(BN + 3) / 4, 256, 0, stream>>>(tmp1, W2, b2, h2, BN);

    // ---- pooling head ----
    graph_mean<<<B, 256, 0, stream>>>(h2, mean, N);
    pathway_score<<<(B * P + 3) / 4 , 256, 0, stream>>>(h2, pathway, mean, wlin, blin, sbuf,
                                                        B, N, P, L);
    out_softmax<<<1, 64, 0, stream>>>(sbuf, Wout, bout, out, B, P);
}

// Round 3
// 680.357 us; speedup vs baseline: 4.7589x; 1.5140x over previous
//
#include <hip/hip_runtime.h>
#include <math.h>

static inline size_t align256(size_t x) { return (x + 255) & ~size_t(255); }

// ============ CSR construction ============

__global__ __launch_bounds__(256) void csr_count(const int* __restrict__ dst,
                                                 int* __restrict__ counts, int E) {
    int e = blockIdx.x * blockDim.x + threadIdx.x;
    if (e >= E) return;
    atomicAdd(&counts[dst[e]], 1);
}

__global__ __launch_bounds__(256) void block_reduce(const int* __restrict__ counts,
                                                    int* __restrict__ bsum, int BN) {
    __shared__ int red[256];
    int base = blockIdx.x * 1024;
    int s = 0;
    for (int k = threadIdx.x; k < 1024; k += 256) {
        int idx = base + k;
        s += (idx < BN) ? counts[idx] : 0;
    }
    red[threadIdx.x] = s;
    __syncthreads();
    for (int off = 128; off >= 1; off >>= 1) {
        if (threadIdx.x < off) red[threadIdx.x] += red[threadIdx.x + off];
        __syncthreads();
    }
    if (threadIdx.x == 0) bsum[blockIdx.x] = red[0];
}

__global__ __launch_bounds__(1024) void scan_small(const int* __restrict__ bsum,
                                                   int* __restrict__ bpre, int nb) {
    __shared__ int buf[1024];
    int tid = threadIdx.x;
    buf[tid] = (tid < nb) ? bsum[tid] : 0;
    __syncthreads();
    for (int off = 1; off < 1024; off <<= 1) {
        int v = (tid >= off) ? buf[tid - off] : 0;
        __syncthreads();
        buf[tid] += v;
        __syncthreads();
    }
    if (tid < nb) bpre[tid] = (tid == 0) ? 0 : buf[tid - 1];
}

__global__ __launch_bounds__(256) void block_scan(const int* __restrict__ counts,
                                                  const int* __restrict__ bpre,
                                                  int* __restrict__ offs, int BN) {
    __shared__ int tsum[256];
    int base = blockIdx.x * 1024;
    int tbase = base + threadIdx.x * 4;
    int c0 = 0, c1 = 0, c2 = 0, c3 = 0;
    if (tbase + 0 < BN) c0 = counts[tbase + 0];
    if (tbase + 1 < BN) c1 = counts[tbase + 1];
    if (tbase + 2 < BN) c2 = counts[tbase + 2];
    if (tbase + 3 < BN) c3 = counts[tbase + 3];
    int local = c0 + c1 + c2 + c3;
    tsum[threadIdx.x] = local;
    __syncthreads();
    for (int off = 1; off < 256; off <<= 1) {
        int v = (threadIdx.x >= off) ? tsum[threadIdx.x - off] : 0;
        __syncthreads();
        tsum[threadIdx.x] += v;
        __syncthreads();
    }
    int prefix = bpre[blockIdx.x] + tsum[threadIdx.x] - local;  // exclusive
    if (tbase + 0 < BN) offs[tbase + 0] = prefix;
    prefix += c0;
    if (tbase + 1 < BN) offs[tbase + 1] = prefix;
    prefix += c1;
    if (tbase + 2 < BN) offs[tbase + 2] = prefix;
    prefix += c2;
    if (tbase + 3 < BN) offs[tbase + 3] = prefix;
}

__global__ __launch_bounds__(256) void csr_fill(const int* __restrict__ src,
                                                const int* __restrict__ dst,
                                                int* __restrict__ cursor,
                                                int* __restrict__ esrc, int E) {
    int e = blockIdx.x * blockDim.x + threadIdx.x;
    if (e >= E) return;
    int d = dst[e];
    int pos = atomicAdd(&cursor[d], 1);
    esrc[pos] = src[e];
}

// ============ gather (self + incoming neighbor sum) ============

__global__ __launch_bounds__(256) void gather16(const float4* __restrict__ h4,
                                                const int* __restrict__ offs,
                                                const int* __restrict__ cnts,
                                                const int* __restrict__ esrc,
                                                float4* __restrict__ out4, int BN) {
    int t = blockIdx.x * blockDim.x + threadIdx.x;
    int i = t >> 2, c = t & 3;
    if (i >= BN) return;
    float4 acc = h4[(size_t)i * 4 + c];
    int start = offs[i], deg = cnts[i];
    for (int j = 0; j < deg; ++j) {
        int s = esrc[start + j];
        float4 v = h4[(size_t)s * 4 + c];
        acc.x += v.x; acc.y += v.y; acc.z += v.z; acc.w += v.w;
    }
    out4[(size_t)i * 4 + c] = acc;
}

__global__ __launch_bounds__(256) void gather64(const float4* __restrict__ h4,
                                                const int* __restrict__ offs,
                                                const int* __restrict__ cnts,
                                                const int* __restrict__ esrc,
                                                float4* __restrict__ out4, int BN) {
    int t = blockIdx.x * blockDim.x + threadIdx.x;
    int i = t >> 4, c = t & 15;
    if (i >= BN) return;
    float4 acc = h4[(size_t)i * 16 + c];
    int start = offs[i], deg = cnts[i];
    for (int j = 0; j < deg; ++j) {
        int s = esrc[start + j];
        float4 v = h4[(size_t)s * 16 + c];
        acc.x += v.x; acc.y += v.y; acc.z += v.z; acc.w += v.w;
    }
    out4[(size_t)i * 16 + c] = acc;
}

// ============ dense layers ============

__global__ __launch_bounds__(256) void lin1_relu(const float* __restrict__ x,
                                                 const float* __restrict__ W1,
                                                 const float* __restrict__ b1,
                                                 float* __restrict__ y, int BN) {
    __shared__ float Ws[16 * 64];
    __shared__ float xs[4][16];
    int tid = threadIdx.x;
    for (int i = tid; i < 16 * 64; i += 256) Ws[i] = W1[i];
    int node0 = blockIdx.x * 4;
    int r = tid >> 6, j = tid & 63;
    if (tid < 64) {
        int nn = tid >> 4, k = tid & 15;
        int node = node0 + nn;
        xs[nn][k] = (node < BN) ? x[(size_t)node * 16 + k] : 0.f;
    }
    __syncthreads();
    int node = node0 + r;
    if (node >= BN) return;
    float acc = b1[j];
#pragma unroll
    for (int k = 0; k < 16; ++k) acc = fmaf(xs[r][k], Ws[k * 64 + j], acc);
    y[(size_t)node * 64 + j] = fmaxf(acc, 0.f);
}

__global__ __launch_bounds__(256) void lin2_relu(const float* __restrict__ x,
                                                 const float* __restrict__ W2,
                                                 const float* __restrict__ b2,
                                                 float* __restrict__ y, int BN) {
    __shared__ float Ws[64 * 64];
    __shared__ float xs[4][64];
    int tid = threadIdx.x;
    for (int i = tid; i < 64 * 64; i += 256) Ws[i] = W2[i];
    int node0 = blockIdx.x * 4;
    int r = tid >> 6, j = tid & 63;
    int node = node0 + r;
    xs[r][j] = (node < BN) ? x[(size_t)node * 64 + j] : 0.f;
    __syncthreads();
    if (node >= BN) return;
    float acc = b2[j];
#pragma unroll
    for (int k = 0; k < 64; ++k) acc = fmaf(xs[r][k], Ws[k * 64 + j], acc);
    y[(size_t)node * 64 + j] = fmaxf(acc, 0.f);
}

// ============ pooling head ============

// 32 blocks per graph; partial sums -> one fp32 HW atomic per (block,feature)
__global__ __launch_bounds__(256) void graph_mean_partial(const float* __restrict__ h2,
                                                          float* __restrict__ meansum,
                                                          int N, int bpg) {
    int b   = blockIdx.x / bpg;
    int sub = blockIdx.x % bpg;
    int tid = threadIdx.x;
    int r = tid >> 6, f = tid & 63;
    const float* base = h2 + (size_t)b * N * 64;
    float acc = 0.f;
    for (int n = sub * 4 + r; n < N; n += bpg * 4) acc += base[(size_t)n * 64 + f];
    __shared__ float red[4][64];
    red[r][f] = acc;
    __syncthreads();
    if (r == 0) {
        float s = red[0][f] + red[1][f] + red[2][f] + red[3][f];
        unsafeAtomicAdd(&meansum[b * 64 + f], s);
    }
}

// per (graph, pathway): sum-pool L nodes; mean term uses meansum * invN
__global__ __launch_bounds__(256) void pathway_score(const float* __restrict__ h2,
                                                     const int* __restrict__ pathway,
                                                     const float* __restrict__ meansum,
                                                     const float* __restrict__ wlin,
                                                     const float* __restrict__ blin,
                                                     float* __restrict__ s,
                                                     int B, int N, int P, int L, float invN) {
    __shared__ int pidx[4][128];
    int wv = threadIdx.x >> 6;
    int lane = threadIdx.x & 63;
    int wid = blockIdx.x * 4 + wv;
    bool active = wid < B * P;
    int b = active ? (wid / P) : 0;
    int p = active ? (wid % P) : 0;
    if (active) {
        const int* path = pathway + (size_t)p * L;
        for (int l = lane; l < L; l += 64) pidx[wv][l] = path[l];
    }
    __syncthreads();
    if (!active) return;
    const float* base = h2 + (size_t)b * N * 64;
    float acc = 0.f;
    int l = 0;
    for (; l + 4 <= L; l += 4) {
        int i0 = pidx[wv][l + 0], i1 = pidx[wv][l + 1];
        int i2 = pidx[wv][l + 2], i3 = pidx[wv][l + 3];
        float v0 = base[(size_t)i0 * 64 + lane];
        float v1 = base[(size_t)i1 * 64 + lane];
        float v2 = base[(size_t)i2 * 64 + lane];
        float v3 = base[(size_t)i3 * 64 + lane];
        acc += (v0 + v1) + (v2 + v3);
    }
    for (; l < L; ++l) acc += base[(size_t)pidx[wv][l] * 64 + lane];
    float val = acc * wlin[64 + lane] + meansum[b * 64 + lane] * invN * wlin[lane];
#pragma unroll
    for (int off = 32; off >= 1; off >>= 1) val += __shfl_xor(val, off, 64);
    if (lane == 0) s[wid] = tanhf(val + blin[0]);
}

__global__ __launch_bounds__(64) void out_softmax(const float* __restrict__ s,
                                                  const float* __restrict__ Wout,
                                                  const float* __restrict__ bout,
                                                  float* __restrict__ out, int B, int P) {
    __shared__ float logits[64];
    int tid = threadIdx.x;
    if (tid < B * 2) {
        int b = tid >> 1, k = tid & 1;
        float acc = bout[k];
        const float* sb = s + (size_t)b * P;
        for (int p = 0; p < P; ++p) acc = fmaf(sb[p], Wout[p * 2 + k], acc);
        logits[tid] = acc;
    }
    __syncthreads();
    if (tid < B) {
        float l0 = logits[tid * 2], l1 = logits[tid * 2 + 1];
        float m = fmaxf(l0, l1);
        float e0 = expf(l0 - m), e1 = expf(l1 - m);
        float inv = 1.f / (e0 + e1);
        out[tid * 2 + 0] = e0 * inv;
        out[tid * 2 + 1] = e1 * inv;
    }
}

extern "C" void kernel_launch(void* const* d_in, const int* in_sizes, int n_in,
                              void* d_out, int out_size, void* d_ws, size_t ws_size,
                              hipStream_t stream) {
    const float* h       = (const float*)d_in[0];
    const int*   src     = (const int*)d_in[1];
    const int*   dst     = (const int*)d_in[2];
    const int*   pathway = (const int*)d_in[3];
    const float* W1      = (const float*)d_in[5];
    const float* b1      = (const float*)d_in[6];
    const float* W2      = (const float*)d_in[7];
    const float* b2      = (const float*)d_in[8];
    const float* wlin    = (const float*)d_in[9];
    const float* blin    = (const float*)d_in[10];
    const float* Wout    = (const float*)d_in[11];
    const float* bout    = (const float*)d_in[12];
    float*       out     = (float*)d_out;

    const int BN = in_sizes[0] / 16;
    const int E  = in_sizes[1];
    const int P  = in_sizes[11] / 2;
    const int L  = in_sizes[3] / P;
    const int B  = out_size / 2;
    const int N  = BN / B;
    const int nb = (BN + 1023) / 1024;

    char* ws = (char*)d_ws;
    size_t o = 0;
    float* tmp0   = (float*)(ws + o); o += align256((size_t)BN * 16 * 4);
    float* h1     = (float*)(ws + o); o += align256((size_t)BN * 64 * 4);
    float* tmp1   = (float*)(ws + o); o += align256((size_t)BN * 64 * 4);
    float* h2     = (float*)(ws + o); o += align256((size_t)BN * 64 * 4);
    float* mean   = (float*)(ws + o); o += align256((size_t)B * 64 * 4);
    float* sbuf   = (float*)(ws + o); o += align256((size_t)B * P * 4);
    int*   counts = (int*)(ws + o);   o += align256((size_t)BN * 4);
    int*   offs   = (int*)(ws + o);   o += align256((size_t)BN * 4);
    int*   cursor = (int*)(ws + o);   o += align256((size_t)BN * 4);
    int*   esrc   = (int*)(ws + o);   o += align256((size_t)E * 4);
    int*   bsum   = (int*)(ws + o);   o += align256((size_t)nb * 4);
    int*   bpre   = (int*)(ws + o);   o += align256((size_t)nb * 4);
    (void)ws_size; (void)n_in;

    // ---- build CSR (dst -> list of src) ----
    hipMemsetAsync(counts, 0, (size_t)BN * 4, stream);
    csr_count<<<(E + 255) / 256, 256, 0, stream>>>(dst, counts, E);
    block_reduce<<<nb, 256, 0, stream>>>(counts, bsum, BN);
    scan_small<<<1, 1024, 0, stream>>>(bsum, bpre, nb);
    block_scan<<<nb, 256, 0, stream>>>(counts, bpre, offs, BN);
    hipMemcpyAsync(cursor, offs, (size_t)BN * 4, hipMemcpyDeviceToDevice, stream);
    csr_fill<<<(E + 255) / 256, 256, 0, stream>>>(src, dst, cursor, esrc, E);

    // ---- layer 1 ----
    gather16<<<(BN * 4 + 255) / 256, 256, 0, stream>>>((const float4*)h, offs, counts, esrc,
                                                       (float4*)tmp0, BN);
    lin1_relu<<<(BN + 3) / 4, 256, 0, stream>>>(tmp0, W1, b1, h1, BN);

    // ---- layer 2 ----
    gather64<<<(BN * 16 + 255) / 256, 256, 0, stream>>>((const float4*)h1, offs, counts, esrc,
                                                        (float4*)tmp1, BN);
    lin2_relu<<<(BN + 3) / 4, 256, 0, stream>>>(tmp1, W2, b2, h2, BN);

    // ---- pooling head ----
    hipMemsetAsync(mean, 0, (size_t)B * 64 * 4, stream);
    {
        const int bpg = 32;  // blocks per graph -> B*32 = 1024 blocks
        graph_mean_partial<<<B * bpg, 256, 0, stream>>>(h2, mean, N, bpg);
    }
    pathway_score<<<(B * P + 3) / 4, 256, 0, stream>>>(h2, pathway, mean, wlin, blin, sbuf,
                                                       B, N, P, L, 1.0f / (float)N);
    out_softmax<<<1, 64, 0, stream>>>(sbuf, Wout, bout, out, B, P);
}

// Round 4
// 490.360 us; speedup vs baseline: 6.6028x; 1.3875x over previous
//
#include <hip/hip_runtime.h>
#include <math.h>

static inline size_t align256(size_t x) { return (x + 255) & ~size_t(255); }

// ============ CSR construction ============

// count + record per-edge rank (atomicAdd return value = unique slot within dst)
__global__ __launch_bounds__(256) void csr_count_rank(const int* __restrict__ dst,
                                                      int* __restrict__ counts,
                                                      int* __restrict__ rank, int E) {
    int e = blockIdx.x * blockDim.x + threadIdx.x;
    if (e >= E) return;
    rank[e] = atomicAdd(&counts[dst[e]], 1);
}

__global__ __launch_bounds__(256) void block_reduce(const int* __restrict__ counts,
                                                    int* __restrict__ bsum, int BN) {
    __shared__ int red[256];
    int base = blockIdx.x * 1024;
    int s = 0;
    for (int k = threadIdx.x; k < 1024; k += 256) {
        int idx = base + k;
        s += (idx < BN) ? counts[idx] : 0;
    }
    red[threadIdx.x] = s;
    __syncthreads();
    for (int off = 128; off >= 1; off >>= 1) {
        if (threadIdx.x < off) red[threadIdx.x] += red[threadIdx.x + off];
        __syncthreads();
    }
    if (threadIdx.x == 0) bsum[blockIdx.x] = red[0];
}

__global__ __launch_bounds__(1024) void scan_small(const int* __restrict__ bsum,
                                                   int* __restrict__ bpre, int nb) {
    __shared__ int buf[1024];
    int tid = threadIdx.x;
    buf[tid] = (tid < nb) ? bsum[tid] : 0;
    __syncthreads();
    for (int off = 1; off < 1024; off <<= 1) {
        int v = (tid >= off) ? buf[tid - off] : 0;
        __syncthreads();
        buf[tid] += v;
        __syncthreads();
    }
    if (tid < nb) bpre[tid] = (tid == 0) ? 0 : buf[tid - 1];
}

__global__ __launch_bounds__(256) void block_scan(const int* __restrict__ counts,
                                                  const int* __restrict__ bpre,
                                                  int* __restrict__ offs, int BN) {
    __shared__ int tsum[256];
    int base = blockIdx.x * 1024;
    int tbase = base + threadIdx.x * 4;
    int c0 = 0, c1 = 0, c2 = 0, c3 = 0;
    if (tbase + 0 < BN) c0 = counts[tbase + 0];
    if (tbase + 1 < BN) c1 = counts[tbase + 1];
    if (tbase + 2 < BN) c2 = counts[tbase + 2];
    if (tbase + 3 < BN) c3 = counts[tbase + 3];
    int local = c0 + c1 + c2 + c3;
    tsum[threadIdx.x] = local;
    __syncthreads();
    for (int off = 1; off < 256; off <<= 1) {
        int v = (threadIdx.x >= off) ? tsum[threadIdx.x - off] : 0;
        __syncthreads();
        tsum[threadIdx.x] += v;
        __syncthreads();
    }
    int prefix = bpre[blockIdx.x] + tsum[threadIdx.x] - local;  // exclusive
    if (tbase + 0 < BN) offs[tbase + 0] = prefix;
    prefix += c0;
    if (tbase + 1 < BN) offs[tbase + 1] = prefix;
    prefix += c1;
    if (tbase + 2 < BN) offs[tbase + 2] = prefix;
    prefix += c2;
    if (tbase + 3 < BN) offs[tbase + 3] = prefix;
}

// fill with NO atomics: pos = offs[dst] + rank
__global__ __launch_bounds__(256) void csr_fill2(const int* __restrict__ src,
                                                 const int* __restrict__ dst,
                                                 const int* __restrict__ rank,
                                                 const int* __restrict__ offs,
                                                 int* __restrict__ esrc, int E) {
    int e = blockIdx.x * blockDim.x + threadIdx.x;
    if (e >= E) return;
    esrc[offs[dst[e]] + rank[e]] = src[e];
}

// ============ layer 1 ============

// agg in 16-dim: 4 lanes per node, float4 each
__global__ __launch_bounds__(256) void gather16(const float4* __restrict__ h4,
                                                const int* __restrict__ offs,
                                                const int* __restrict__ cnts,
                                                const int* __restrict__ esrc,
                                                float4* __restrict__ out4, int BN) {
    int t = blockIdx.x * blockDim.x + threadIdx.x;
    int i = t >> 2, c = t & 3;
    if (i >= BN) return;
    float4 acc = h4[(size_t)i * 4 + c];
    int start = offs[i], deg = cnts[i];
    int j = 0;
    for (; j + 4 <= deg; j += 4) {
        int s0 = esrc[start + j], s1 = esrc[start + j + 1];
        int s2 = esrc[start + j + 2], s3 = esrc[start + j + 3];
        float4 v0 = h4[(size_t)s0 * 4 + c];
        float4 v1 = h4[(size_t)s1 * 4 + c];
        float4 v2 = h4[(size_t)s2 * 4 + c];
        float4 v3 = h4[(size_t)s3 * 4 + c];
        acc.x += (v0.x + v1.x) + (v2.x + v3.x);
        acc.y += (v0.y + v1.y) + (v2.y + v3.y);
        acc.z += (v0.z + v1.z) + (v2.z + v3.z);
        acc.w += (v0.w + v1.w) + (v2.w + v3.w);
    }
    for (; j < deg; ++j) {
        int s = esrc[start + j];
        float4 v = h4[(size_t)s * 4 + c];
        acc.x += v.x; acc.y += v.y; acc.z += v.z; acc.w += v.w;
    }
    out4[(size_t)i * 4 + c] = acc;
}

// h1 = relu(x @ W1 + b1): one wave per node, W1 column j in 16 regs
__global__ __launch_bounds__(256) void lin1_wave(const float* __restrict__ x,
                                                 const float* __restrict__ W1,
                                                 const float* __restrict__ b1,
                                                 float* __restrict__ y, int BN) {
    int tid = threadIdx.x;
    int lane = tid & 63;
    int gw = (int)((blockIdx.x * blockDim.x + tid) >> 6);
    int nw = (int)((gridDim.x * blockDim.x) >> 6);
    float wcol[16];
#pragma unroll
    for (int k = 0; k < 16; ++k) wcol[k] = W1[k * 64 + lane];
    float breg = b1[lane];
    for (int i = gw; i < BN; i += nw) {
        float x0 = x[(size_t)i * 16 + (lane & 15)];
        float acc = breg;
#pragma unroll
        for (int k = 0; k < 16; ++k) acc = fmaf(__shfl(x0, k, 64), wcol[k], acc);
        y[(size_t)i * 64 + lane] = fmaxf(acc, 0.f);
    }
}

// ============ fused layer 2: gather + lin2 + relu + project to (q, r) ============
// wave per node. lane j holds feature j. h2 never materialized.
// q[i] = h2_i . wlin[64:128]  (pathway sum-pool term)
// r[i] = h2_i . wlin[0:64]    (graph-mean term)
__global__ __launch_bounds__(256, 4) void gather64_lin2_qr(const float* __restrict__ h1,
                                                           const int* __restrict__ offs,
                                                           const int* __restrict__ cnts,
                                                           const int* __restrict__ esrc,
                                                           const float* __restrict__ W2,
                                                           const float* __restrict__ b2,
                                                           const float* __restrict__ wlin,
                                                           float* __restrict__ q,
                                                           float* __restrict__ r, int BN) {
    int tid = threadIdx.x;
    int lane = tid & 63;
    int gw = (int)((blockIdx.x * blockDim.x + tid) >> 6);
    int nw = (int)((gridDim.x * blockDim.x) >> 6);
    float wcol[64];
#pragma unroll
    for (int k = 0; k < 64; ++k) wcol[k] = W2[k * 64 + lane];
    float breg = b2[lane];
    float wlo = wlin[lane];
    float whi = wlin[64 + lane];
    for (int i = gw; i < BN; i += nw) {
        // gather: x_j = h1[i][j] + sum_{s in N(i)} h1[s][j]
        float acc = h1[(size_t)i * 64 + lane];
        int start = offs[i], deg = cnts[i];
        for (int j0 = 0; j0 < deg; j0 += 64) {
            int idx = 0;
            if (j0 + lane < deg) idx = esrc[start + j0 + lane];
            int m = min(64, deg - j0);
            int jj = 0;
            for (; jj + 4 <= m; jj += 4) {
                int s0 = __shfl(idx, jj + 0, 64);
                int s1 = __shfl(idx, jj + 1, 64);
                int s2 = __shfl(idx, jj + 2, 64);
                int s3 = __shfl(idx, jj + 3, 64);
                float v0 = h1[(size_t)s0 * 64 + lane];
                float v1 = h1[(size_t)s1 * 64 + lane];
                float v2 = h1[(size_t)s2 * 64 + lane];
                float v3 = h1[(size_t)s3 * 64 + lane];
                acc += (v0 + v1) + (v2 + v3);
            }
            for (; jj < m; ++jj) {
                int s = __shfl(idx, jj, 64);
                acc += h1[(size_t)s * 64 + lane];
            }
        }
        // lin2: out_j = b2[j] + sum_k x_k * W2[k][j]
        float out = breg;
#pragma unroll
        for (int k = 0; k < 64; ++k) out = fmaf(__shfl(acc, k, 64), wcol[k], out);
        float h2v = fmaxf(out, 0.f);
        // project
        float qv = h2v * whi;
        float rv = h2v * wlo;
#pragma unroll
        for (int off = 32; off >= 1; off >>= 1) {
            qv += __shfl_xor(qv, off, 64);
            rv += __shfl_xor(rv, off, 64);
        }
        if (lane == 0) {
            q[i] = qv;
            r[i] = rv;
        }
    }
}

// ============ pooling head ============

// m2[b] = sum_n r[b*N+n]
__global__ __launch_bounds__(256) void reduce_m2(const float* __restrict__ r,
                                                 float* __restrict__ m2, int N, int bpg) {
    int b = blockIdx.x / bpg, sub = blockIdx.x % bpg;
    const float* rb = r + (size_t)b * N;
    float a = 0.f;
    for (int n = sub * 256 + threadIdx.x; n < N; n += bpg * 256) a += rb[n];
    __shared__ float red[256];
    red[threadIdx.x] = a;
    __syncthreads();
    for (int off = 128; off >= 1; off >>= 1) {
        if (threadIdx.x < off) red[threadIdx.x] += red[threadIdx.x + off];
        __syncthreads();
    }
    if (threadIdx.x == 0) unsafeAtomicAdd(&m2[b], red[0]);
}

// s[b*P+p] = tanh( sum_l q[b*N + path[p][l]] + m2[b]/N + blin )
__global__ __launch_bounds__(256) void pathway_score2(const float* __restrict__ q,
                                                      const int* __restrict__ pathway,
                                                      const float* __restrict__ m2,
                                                      const float* __restrict__ blin,
                                                      float* __restrict__ s,
                                                      int N, int P, int L, float invN,
                                                      int pgpb) {
    extern __shared__ float ldsq[];
    int b = blockIdx.x / pgpb, sub = blockIdx.x % pgpb;
    const float* qb = q + (size_t)b * N;
    for (int n = threadIdx.x; n < N; n += 256) ldsq[n] = qb[n];
    __syncthreads();
    float mterm = m2[b] * invN + blin[0];
    for (int p = sub * 256 + threadIdx.x; p < P; p += pgpb * 256) {
        const int* pw = pathway + (size_t)p * L;
        float sum = 0.f;
        for (int l = 0; l < L; ++l) sum += ldsq[pw[l]];
        s[(size_t)b * P + p] = tanhf(sum + mterm);
    }
}

__global__ __launch_bounds__(64) void out_softmax(const float* __restrict__ s,
                                                  const float* __restrict__ Wout,
                                                  const float* __restrict__ bout,
                                                  float* __restrict__ out, int B, int P) {
    __shared__ float logits[64];
    int tid = threadIdx.x;
    if (tid < B * 2) {
        int b = tid >> 1, k = tid & 1;
        float acc = bout[k];
        const float* sb = s + (size_t)b * P;
        for (int p = 0; p < P; ++p) acc = fmaf(sb[p], Wout[p * 2 + k], acc);
        logits[tid] = acc;
    }
    __syncthreads();
    if (tid < B) {
        float l0 = logits[tid * 2], l1 = logits[tid * 2 + 1];
        float m = fmaxf(l0, l1);
        float e0 = expf(l0 - m), e1 = expf(l1 - m);
        float inv = 1.f / (e0 + e1);
        out[tid * 2 + 0] = e0 * inv;
        out[tid * 2 + 1] = e1 * inv;
    }
}

extern "C" void kernel_launch(void* const* d_in, const int* in_sizes, int n_in,
                              void* d_out, int out_size, void* d_ws, size_t ws_size,
                              hipStream_t stream) {
    const float* h       = (const float*)d_in[0];
    const int*   src     = (const int*)d_in[1];
    const int*   dst     = (const int*)d_in[2];
    const int*   pathway = (const int*)d_in[3];
    const float* W1      = (const float*)d_in[5];
    const float* b1      = (const float*)d_in[6];
    const float* W2      = (const float*)d_in[7];
    const float* b2      = (const float*)d_in[8];
    const float* wlin    = (const float*)d_in[9];
    const float* blin    = (const float*)d_in[10];
    const float* Wout    = (const float*)d_in[11];
    const float* bout    = (const float*)d_in[12];
    float*       out     = (float*)d_out;

    const int BN = in_sizes[0] / 16;
    const int E  = in_sizes[1];
    const int P  = in_sizes[11] / 2;
    const int L  = in_sizes[3] / P;
    const int B  = out_size / 2;
    const int N  = BN / B;
    const int nb = (BN + 1023) / 1024;

    char* ws = (char*)d_ws;
    size_t o = 0;
    float* tmp0   = (float*)(ws + o); o += align256((size_t)BN * 16 * 4);
    float* h1     = (float*)(ws + o); o += align256((size_t)BN * 64 * 4);
    float* qbuf   = (float*)(ws + o); o += align256((size_t)BN * 4);
    float* rbuf   = (float*)(ws + o); o += align256((size_t)BN * 4);
    float* m2     = (float*)(ws + o); o += align256((size_t)B * 4);
    float* sbuf   = (float*)(ws + o); o += align256((size_t)B * P * 4);
    int*   counts = (int*)(ws + o);   o += align256((size_t)BN * 4);
    int*   offs   = (int*)(ws + o);   o += align256((size_t)BN * 4);
    int*   rank   = (int*)(ws + o);   o += align256((size_t)E * 4);
    int*   esrc   = (int*)(ws + o);   o += align256((size_t)E * 4);
    int*   bsum   = (int*)(ws + o);   o += align256((size_t)nb * 4);
    int*   bpre   = (int*)(ws + o);   o += align256((size_t)nb * 4);
    (void)ws_size; (void)n_in;

    // ---- build CSR (dst -> list of src), fill has no atomics ----
    hipMemsetAsync(counts, 0, (size_t)BN * 4, stream);
    hipMemsetAsync(m2, 0, (size_t)B * 4, stream);
    csr_count_rank<<<(E + 255) / 256, 256, 0, stream>>>(dst, counts, rank, E);
    block_reduce<<<nb, 256, 0, stream>>>(counts, bsum, BN);
    scan_small<<<1, 1024, 0, stream>>>(bsum, bpre, nb);
    block_scan<<<nb, 256, 0, stream>>>(counts, bpre, offs, BN);
    csr_fill2<<<(E + 255) / 256, 256, 0, stream>>>(src, dst, rank, offs, esrc, E);

    // ---- layer 1 ----
    gather16<<<(BN * 4 + 255) / 256, 256, 0, stream>>>((const float4*)h, offs, counts, esrc,
                                                       (float4*)tmp0, BN);
    lin1_wave<<<2048, 256, 0, stream>>>(tmp0, W1, b1, h1, BN);

    // ---- fused layer 2 + projection (h2 never materialized) ----
    gather64_lin2_qr<<<2048, 256, 0, stream>>>(h1, offs, counts, esrc, W2, b2, wlin,
                                               qbuf, rbuf, BN);

    // ---- pooling head ----
    reduce_m2<<<B * 8, 256, 0, stream>>>(rbuf, m2, N, 8);
    {
        const int pgpb = 2;
        pathway_score2<<<B * pgpb, 256, (size_t)N * 4, stream>>>(qbuf, pathway, m2, blin, sbuf,
                                                                 N, P, L, 1.0f / (float)N, pgpb);
    }
    out_softmax<<<1, 64, 0, stream>>>(sbuf, Wout, bout, out, B, P);
}

// Round 5
// 396.122 us; speedup vs baseline: 8.1737x; 1.2379x over previous
//
#include <hip/hip_runtime.h>
#include <math.h>

static inline size_t align256(size_t x) { return (x + 255) & ~size_t(255); }

// ============ CSR construction ============

// count + record per-edge rank (atomicAdd return value = unique slot within dst)
__global__ __launch_bounds__(256) void csr_count_rank(const int* __restrict__ dst,
                                                      int* __restrict__ counts,
                                                      int* __restrict__ rank, int E) {
    int e = blockIdx.x * blockDim.x + threadIdx.x;
    if (e >= E) return;
    rank[e] = atomicAdd(&counts[dst[e]], 1);
}

__global__ __launch_bounds__(256) void block_reduce(const int* __restrict__ counts,
                                                    int* __restrict__ bsum, int BN) {
    __shared__ int red[256];
    int base = blockIdx.x * 1024;
    int s = 0;
    for (int k = threadIdx.x; k < 1024; k += 256) {
        int idx = base + k;
        s += (idx < BN) ? counts[idx] : 0;
    }
    red[threadIdx.x] = s;
    __syncthreads();
    for (int off = 128; off >= 1; off >>= 1) {
        if (threadIdx.x < off) red[threadIdx.x] += red[threadIdx.x + off];
        __syncthreads();
    }
    if (threadIdx.x == 0) bsum[blockIdx.x] = red[0];
}

__global__ __launch_bounds__(1024) void scan_small(const int* __restrict__ bsum,
                                                   int* __restrict__ bpre, int nb) {
    __shared__ int buf[1024];
    int tid = threadIdx.x;
    buf[tid] = (tid < nb) ? bsum[tid] : 0;
    __syncthreads();
    for (int off = 1; off < 1024; off <<= 1) {
        int v = (tid >= off) ? buf[tid - off] : 0;
        __syncthreads();
        buf[tid] += v;
        __syncthreads();
    }
    if (tid < nb) bpre[tid] = (tid == 0) ? 0 : buf[tid - 1];
}

__global__ __launch_bounds__(256) void block_scan(const int* __restrict__ counts,
                                                  const int* __restrict__ bpre,
                                                  int* __restrict__ offs, int BN) {
    __shared__ int tsum[256];
    int base = blockIdx.x * 1024;
    int tbase = base + threadIdx.x * 4;
    int c0 = 0, c1 = 0, c2 = 0, c3 = 0;
    if (tbase + 0 < BN) c0 = counts[tbase + 0];
    if (tbase + 1 < BN) c1 = counts[tbase + 1];
    if (tbase + 2 < BN) c2 = counts[tbase + 2];
    if (tbase + 3 < BN) c3 = counts[tbase + 3];
    int local = c0 + c1 + c2 + c3;
    tsum[threadIdx.x] = local;
    __syncthreads();
    for (int off = 1; off < 256; off <<= 1) {
        int v = (threadIdx.x >= off) ? tsum[threadIdx.x - off] : 0;
        __syncthreads();
        tsum[threadIdx.x] += v;
        __syncthreads();
    }
    int prefix = bpre[blockIdx.x] + tsum[threadIdx.x] - local;  // exclusive
    if (tbase + 0 < BN) offs[tbase + 0] = prefix;
    prefix += c0;
    if (tbase + 1 < BN) offs[tbase + 1] = prefix;
    prefix += c1;
    if (tbase + 2 < BN) offs[tbase + 2] = prefix;
    prefix += c2;
    if (tbase + 3 < BN) offs[tbase + 3] = prefix;
}

// fill with NO atomics: pos = offs[dst] + rank
__global__ __launch_bounds__(256) void csr_fill2(const int* __restrict__ src,
                                                 const int* __restrict__ dst,
                                                 const int* __restrict__ rank,
                                                 const int* __restrict__ offs,
                                                 int* __restrict__ esrc, int E) {
    int e = blockIdx.x * blockDim.x + threadIdx.x;
    if (e >= E) return;
    esrc[offs[dst[e]] + rank[e]] = src[e];
}

// ============ layer 1 ============

// agg in 16-dim: 4 lanes per node, float4 each
__global__ __launch_bounds__(256) void gather16(const float4* __restrict__ h4,
                                                const int* __restrict__ offs,
                                                const int* __restrict__ cnts,
                                                const int* __restrict__ esrc,
                                                float4* __restrict__ out4, int BN) {
    int t = blockIdx.x * blockDim.x + threadIdx.x;
    int i = t >> 2, c = t & 3;
    if (i >= BN) return;
    float4 acc = h4[(size_t)i * 4 + c];
    int start = offs[i], deg = cnts[i];
    int j = 0;
    for (; j + 4 <= deg; j += 4) {
        int s0 = esrc[start + j], s1 = esrc[start + j + 1];
        int s2 = esrc[start + j + 2], s3 = esrc[start + j + 3];
        float4 v0 = h4[(size_t)s0 * 4 + c];
        float4 v1 = h4[(size_t)s1 * 4 + c];
        float4 v2 = h4[(size_t)s2 * 4 + c];
        float4 v3 = h4[(size_t)s3 * 4 + c];
        acc.x += (v0.x + v1.x) + (v2.x + v3.x);
        acc.y += (v0.y + v1.y) + (v2.y + v3.y);
        acc.z += (v0.z + v1.z) + (v2.z + v3.z);
        acc.w += (v0.w + v1.w) + (v2.w + v3.w);
    }
    for (; j < deg; ++j) {
        int s = esrc[start + j];
        float4 v = h4[(size_t)s * 4 + c];
        acc.x += v.x; acc.y += v.y; acc.z += v.z; acc.w += v.w;
    }
    out4[(size_t)i * 4 + c] = acc;
}

// h1 = relu(x @ W1 + b1): one wave per node, W1 column in 16 regs,
// x broadcast via uniform-address LDS reads (no shfl)
__global__ __launch_bounds__(256) void lin1_wave(const float* __restrict__ x,
                                                 const float* __restrict__ W1,
                                                 const float* __restrict__ b1,
                                                 float* __restrict__ y, int BN) {
    __shared__ float xb[4][16];
    int tid = threadIdx.x;
    int lane = tid & 63, wv = tid >> 6;
    int gw = (int)((blockIdx.x * blockDim.x + tid) >> 6);
    int nw = (int)((gridDim.x * blockDim.x) >> 6);
    float wcol[16];
#pragma unroll
    for (int k = 0; k < 16; ++k) wcol[k] = W1[k * 64 + lane];
    float breg = b1[lane];
    for (int i = gw; i < BN; i += nw) {
        float x0 = x[(size_t)i * 16 + (lane & 15)];
        if (lane < 16) xb[wv][lane] = x0;
        float acc = breg;
#pragma unroll
        for (int k4 = 0; k4 < 4; ++k4) {
            float4 xv = *(const float4*)&xb[wv][k4 * 4];
            acc = fmaf(xv.x, wcol[k4 * 4 + 0], acc);
            acc = fmaf(xv.y, wcol[k4 * 4 + 1], acc);
            acc = fmaf(xv.z, wcol[k4 * 4 + 2], acc);
            acc = fmaf(xv.w, wcol[k4 * 4 + 3], acc);
        }
        y[(size_t)i * 64 + lane] = fmaxf(acc, 0.f);
    }
}

// ============ fused layer 2: gather + lin2 + relu + project to (q, r) ============
// wave per node, lane = feature. Broadcasts via uniform LDS reads, not shfl.
__global__ __launch_bounds__(256, 4) void gather64_lin2_qr(const float* __restrict__ h1,
                                                           const int* __restrict__ offs,
                                                           const int* __restrict__ cnts,
                                                           const int* __restrict__ esrc,
                                                           const float* __restrict__ W2,
                                                           const float* __restrict__ b2,
                                                           const float* __restrict__ wlin,
                                                           float* __restrict__ q,
                                                           float* __restrict__ r, int BN) {
    __shared__ float xbuf[4][64];
    __shared__ int   ibuf[4][64];
    int tid = threadIdx.x;
    int lane = tid & 63, wv = tid >> 6;
    int gw = (int)((blockIdx.x * blockDim.x + tid) >> 6);
    int nw = (int)((gridDim.x * blockDim.x) >> 6);
    float wcol[64];
#pragma unroll
    for (int k = 0; k < 64; ++k) wcol[k] = W2[k * 64 + lane];
    float breg = b2[lane];
    float wlo = wlin[lane];
    float whi = wlin[64 + lane];
    const float* hl = h1 + lane;
    for (int i = gw; i < BN; i += nw) {
        float acc = hl[(size_t)i * 64];
        int start = offs[i], deg = cnts[i];
        for (int j0 = 0; j0 < deg; j0 += 64) {
            int m = min(64, deg - j0);
            if (lane < m) ibuf[wv][lane] = esrc[start + j0 + lane];
            int jj = 0;
            for (; jj + 8 <= m; jj += 8) {
                int4 ia = *(const int4*)&ibuf[wv][jj];
                int4 ib = *(const int4*)&ibuf[wv][jj + 4];
                float v0 = hl[(size_t)ia.x * 64];
                float v1 = hl[(size_t)ia.y * 64];
                float v2 = hl[(size_t)ia.z * 64];
                float v3 = hl[(size_t)ia.w * 64];
                float v4 = hl[(size_t)ib.x * 64];
                float v5 = hl[(size_t)ib.y * 64];
                float v6 = hl[(size_t)ib.z * 64];
                float v7 = hl[(size_t)ib.w * 64];
                acc += ((v0 + v1) + (v2 + v3)) + ((v4 + v5) + (v6 + v7));
            }
            for (; jj + 4 <= m; jj += 4) {
                int4 ia = *(const int4*)&ibuf[wv][jj];
                float v0 = hl[(size_t)ia.x * 64];
                float v1 = hl[(size_t)ia.y * 64];
                float v2 = hl[(size_t)ia.z * 64];
                float v3 = hl[(size_t)ia.w * 64];
                acc += (v0 + v1) + (v2 + v3);
            }
            for (; jj < m; ++jj) acc += hl[(size_t)ibuf[wv][jj] * 64];
        }
        // lin2 matvec: broadcast gathered row via uniform ds_read_b128
        xbuf[wv][lane] = acc;
        float outv = breg;
#pragma unroll
        for (int k4 = 0; k4 < 16; ++k4) {
            float4 xv = *(const float4*)&xbuf[wv][k4 * 4];
            outv = fmaf(xv.x, wcol[k4 * 4 + 0], outv);
            outv = fmaf(xv.y, wcol[k4 * 4 + 1], outv);
            outv = fmaf(xv.z, wcol[k4 * 4 + 2], outv);
            outv = fmaf(xv.w, wcol[k4 * 4 + 3], outv);
        }
        float h2v = fmaxf(outv, 0.f);
        float qv = h2v * whi;
        float rv = h2v * wlo;
#pragma unroll
        for (int off = 32; off >= 1; off >>= 1) {
            qv += __shfl_xor(qv, off, 64);
            rv += __shfl_xor(rv, off, 64);
        }
        if (lane == 0) {
            q[i] = qv;
            r[i] = rv;
        }
    }
}

// ============ pooling head ============

__global__ __launch_bounds__(256) void reduce_m2(const float* __restrict__ r,
                                                 float* __restrict__ m2, int N, int bpg) {
    int b = blockIdx.x / bpg, sub = blockIdx.x % bpg;
    const float* rb = r + (size_t)b * N;
    float a = 0.f;
    for (int n = sub * 256 + threadIdx.x; n < N; n += bpg * 256) a += rb[n];
    __shared__ float red[256];
    red[threadIdx.x] = a;
    __syncthreads();
    for (int off = 128; off >= 1; off >>= 1) {
        if (threadIdx.x < off) red[threadIdx.x] += red[threadIdx.x + off];
        __syncthreads();
    }
    if (threadIdx.x == 0) unsafeAtomicAdd(&m2[b], red[0]);
}

__global__ __launch_bounds__(256) void pathway_score2(const float* __restrict__ q,
                                                      const int* __restrict__ pathway,
                                                      const float* __restrict__ m2,
                                                      const float* __restrict__ blin,
                                                      float* __restrict__ s,
                                                      int N, int P, int L, float invN,
                                                      int pgpb) {
    extern __shared__ float ldsq[];
    int b = blockIdx.x / pgpb, sub = blockIdx.x % pgpb;
    const float* qb = q + (size_t)b * N;
    for (int n = threadIdx.x; n < N; n += 256) ldsq[n] = qb[n];
    __syncthreads();
    float mterm = m2[b] * invN + blin[0];
    for (int p = sub * 256 + threadIdx.x; p < P; p += pgpb * 256) {
        const int* pw = pathway + (size_t)p * L;
        float sum = 0.f;
        for (int l = 0; l < L; ++l) sum += ldsq[pw[l]];
        s[(size_t)b * P + p] = tanhf(sum + mterm);
    }
}

__global__ __launch_bounds__(64) void out_softmax(const float* __restrict__ s,
                                                  const float* __restrict__ Wout,
                                                  const float* __restrict__ bout,
                                                  float* __restrict__ out, int B, int P) {
    __shared__ float logits[64];
    int tid = threadIdx.x;
    if (tid < B * 2) {
        int b = tid >> 1, k = tid & 1;
        float acc = bout[k];
        const float* sb = s + (size_t)b * P;
        for (int p = 0; p < P; ++p) acc = fmaf(sb[p], Wout[p * 2 + k], acc);
        logits[tid] = acc;
    }
    __syncthreads();
    if (tid < B) {
        float l0 = logits[tid * 2], l1 = logits[tid * 2 + 1];
        float m = fmaxf(l0, l1);
        float e0 = expf(l0 - m), e1 = expf(l1 - m);
        float inv = 1.f / (e0 + e1);
        out[tid * 2 + 0] = e0 * inv;
        out[tid * 2 + 1] = e1 * inv;
    }
}

extern "C" void kernel_launch(void* const* d_in, const int* in_sizes, int n_in,
                              void* d_out, int out_size, void* d_ws, size_t ws_size,
                              hipStream_t stream) {
    const float* h       = (const float*)d_in[0];
    const int*   src     = (const int*)d_in[1];
    const int*   dst     = (const int*)d_in[2];
    const int*   pathway = (const int*)d_in[3];
    const float* W1      = (const float*)d_in[5];
    const float* b1      = (const float*)d_in[6];
    const float* W2      = (const float*)d_in[7];
    const float* b2      = (const float*)d_in[8];
    const float* wlin    = (const float*)d_in[9];
    const float* blin    = (const float*)d_in[10];
    const float* Wout    = (const float*)d_in[11];
    const float* bout    = (const float*)d_in[12];
    float*       out     = (float*)d_out;

    const int BN = in_sizes[0] / 16;
    const int E  = in_sizes[1];
    const int P  = in_sizes[11] / 2;
    const int L  = in_sizes[3] / P;
    const int B  = out_size / 2;
    const int N  = BN / B;
    const int nb = (BN + 1023) / 1024;

    char* ws = (char*)d_ws;
    size_t o = 0;
    float* tmp0   = (float*)(ws + o); o += align256((size_t)BN * 16 * 4);
    float* h1     = (float*)(ws + o); o += align256((size_t)BN * 64 * 4);
    float* qbuf   = (float*)(ws + o); o += align256((size_t)BN * 4);
    float* rbuf   = (float*)(ws + o); o += align256((size_t)BN * 4);
    float* m2     = (float*)(ws + o); o += align256((size_t)B * 4);
    float* sbuf   = (float*)(ws + o); o += align256((size_t)B * P * 4);
    int*   counts = (int*)(ws + o);   o += align256((size_t)BN * 4);
    int*   offs   = (int*)(ws + o);   o += align256((size_t)BN * 4);
    int*   rank   = (int*)(ws + o);   o += align256((size_t)E * 4);
    int*   esrc   = (int*)(ws + o);   o += align256((size_t)E * 4);
    int*   bsum   = (int*)(ws + o);   o += align256((size_t)nb * 4);
    int*   bpre   = (int*)(ws + o);   o += align256((size_t)nb * 4);
    (void)ws_size; (void)n_in;

    // ---- build CSR (dst -> list of src), fill has no atomics ----
    hipMemsetAsync(counts, 0, (size_t)BN * 4, stream);
    hipMemsetAsync(m2, 0, (size_t)B * 4, stream);
    csr_count_rank<<<(E + 255) / 256, 256, 0, stream>>>(dst, counts, rank, E);
    block_reduce<<<nb, 256, 0, stream>>>(counts, bsum, BN);
    scan_small<<<1, 1024, 0, stream>>>(bsum, bpre, nb);
    block_scan<<<nb, 256, 0, stream>>>(counts, bpre, offs, BN);
    csr_fill2<<<(E + 255) / 256, 256, 0, stream>>>(src, dst, rank, offs, esrc, E);

    // ---- layer 1 ----
    gather16<<<(BN * 4 + 255) / 256, 256, 0, stream>>>((const float4*)h, offs, counts, esrc,
                                                       (float4*)tmp0, BN);
    lin1_wave<<<2048, 256, 0, stream>>>(tmp0, W1, b1, h1, BN);

    // ---- fused layer 2 + projection (h2 never materialized) ----
    gather64_lin2_qr<<<2048, 256, 0, stream>>>(h1, offs, counts, esrc, W2, b2, wlin,
                                               qbuf, rbuf, BN);

    // ---- pooling head ----
    reduce_m2<<<B * 8, 256, 0, stream>>>(rbuf, m2, N, 8);
    {
        const int pgpb = 2;
        pathway_score2<<<B * pgpb, 256, (size_t)N * 4, stream>>>(qbuf, pathway, m2, blin, sbuf,
                                                                 N, P, L, 1.0f / (float)N, pgpb);
    }
    out_softmax<<<1, 64, 0, stream>>>(sbuf, Wout, bout, out, B, P);
}